// Round 1
// baseline (2145.925 us; speedup 1.0000x reference)
//
#include <hip/hip_runtime.h>
#include <hip/hip_bf16.h>
#include <stdint.h>

// ---------------------------------------------------------------------------
// GraphEncoder: emb-lookup -> elu(emb@W_eh^T+b) -> 48-step attention-GRU scan
// Round 1: bf16-MFMA embed GEMM + persistent cooperative scan kernel.
// ---------------------------------------------------------------------------

typedef __bf16 bf16_t;
typedef __bf16 bf16x8 __attribute__((ext_vector_type(8)));
typedef float  f32x4  __attribute__((ext_vector_type(4)));

#define MFMA16(a,b,c) __builtin_amdgcn_mfma_f32_16x16x32_bf16((a),(b),(c),0,0,0)

// ---- workspace layout (bytes) ----
static constexpr size_t SZ_MEM   = 48ull*32*64*512*2;      // 100,663,296 bf16 mem[sent][b][s][h]
static constexpr size_t OFF_WA   = SZ_MEM;                 // [W_in;W_hh] bf16 [2048][512]
static constexpr size_t SZ_WA    = 2048ull*512*2;
static constexpr size_t OFF_WOUT = OFF_WA + SZ_WA;         // W_out bf16 [512][1024]
static constexpr size_t SZ_WOUT  = 512ull*1024*2;
static constexpr size_t OFF_WIH  = OFF_WOUT + SZ_WOUT;     // W_ih bf16 [1536][512]
static constexpr size_t SZ_WIH   = 1536ull*512*2;
static constexpr size_t OFF_LEN  = OFF_WIH + SZ_WIH;       // int[1536]
static constexpr size_t OFF_H    = OFF_LEN + 8192;         // f32 [32][512]
static constexpr size_t OFF_HBF  = OFF_H + 65536;          // bf16 [32][512]
static constexpr size_t OFF_Q    = OFF_HBF + 32768;        // f32 [32][512]
static constexpr size_t OFF_GH   = OFF_Q + 65536;          // f32 [32][1536]
static constexpr size_t OFF_CBF  = OFF_GH + 196608;        // bf16 [32][512]
static constexpr size_t OFF_XBF  = OFF_CBF + 32768;        // bf16 [32][512]
static constexpr size_t OFF_BAR  = OFF_XBF + 32768;        // barrier counter
static constexpr size_t WS_NEED  = OFF_BAR + 256;

// ---- helpers ----
__device__ __forceinline__ unsigned ld_a32(const void* p) {
  return __hip_atomic_load((const unsigned*)p, __ATOMIC_RELAXED, __HIP_MEMORY_SCOPE_AGENT);
}
__device__ __forceinline__ unsigned long long ld_a64(const void* p) {
  return __hip_atomic_load((const unsigned long long*)p, __ATOMIC_RELAXED, __HIP_MEMORY_SCOPE_AGENT);
}
__device__ __forceinline__ void st_a32(void* p, unsigned v) {
  __hip_atomic_store((unsigned*)p, v, __ATOMIC_RELAXED, __HIP_MEMORY_SCOPE_AGENT);
}
__device__ __forceinline__ void st_a64(void* p, unsigned long long v) {
  __hip_atomic_store((unsigned long long*)p, v, __ATOMIC_RELAXED, __HIP_MEMORY_SCOPE_AGENT);
}
__device__ __forceinline__ float2 bf2f(unsigned u) {
  float2 r;
  unsigned lo = u << 16, hi = u & 0xffff0000u;
  r.x = __builtin_bit_cast(float, lo);
  r.y = __builtin_bit_cast(float, hi);
  return r;
}
__device__ __forceinline__ unsigned pack_bf2(float a, float b) {
  __bf16 ba = (__bf16)a, bb = (__bf16)b;
  unsigned short ua = __builtin_bit_cast(unsigned short, ba);
  unsigned short ub = __builtin_bit_cast(unsigned short, bb);
  return (unsigned)ua | ((unsigned)ub << 16);
}
__device__ __forceinline__ bf16x8 cvt8(float4 lo, float4 hi) {
  bf16x8 v;
  v[0]=(__bf16)lo.x; v[1]=(__bf16)lo.y; v[2]=(__bf16)lo.z; v[3]=(__bf16)lo.w;
  v[4]=(__bf16)hi.x; v[5]=(__bf16)hi.y; v[6]=(__bf16)hi.z; v[7]=(__bf16)hi.w;
  return v;
}
// monotonic-counter grid barrier (32 resident blocks; counter memset to 0 per launch)
__device__ __forceinline__ void gbar(unsigned* cnt, int target) {
  __syncthreads();
  if (threadIdx.x == 0) {
    __hip_atomic_fetch_add(cnt, 1u, __ATOMIC_RELEASE, __HIP_MEMORY_SCOPE_AGENT);
    while ((int)__hip_atomic_load(cnt, __ATOMIC_ACQUIRE, __HIP_MEMORY_SCOPE_AGENT) < target) {
      __builtin_amdgcn_s_sleep(1);
    }
  }
  __syncthreads();
}

// ---- prep: convert weights to bf16 ----
__global__ __launch_bounds__(256) void prep_weights(
    const float* __restrict__ Win, const float* __restrict__ Whh,
    const float* __restrict__ Wout, const float* __restrict__ Wih,
    bf16_t* __restrict__ WA, bf16_t* __restrict__ WoutB, bf16_t* __restrict__ WihB)
{
  int idx = blockIdx.x * 256 + threadIdx.x;
  if (idx < 262144)        WA[idx]            = (__bf16)Win[idx];
  else if (idx < 1048576)  WA[idx]            = (__bf16)Whh[idx - 262144];
  else if (idx < 1572864)  WoutB[idx-1048576] = (__bf16)Wout[idx - 1048576];
  else if (idx < 2359296)  WihB[idx-1572864]  = (__bf16)Wih[idx - 1572864];
}

__global__ __launch_bounds__(256) void h_init(
    const float* __restrict__ h0, float* __restrict__ h, bf16_t* __restrict__ hbf)
{
  int idx = blockIdx.x * 256 + threadIdx.x;   // 16384
  float v = h0[idx & 511];
  h[idx] = v;
  hbf[idx] = (__bf16)v;
}

__global__ __launch_bounds__(256) void lengths_kernel(
    const int* __restrict__ cpt, int* __restrict__ len)
{
  int r = blockIdx.x * 256 + threadIdx.x;
  if (r < 1536) {
    int c = 0;
    for (int s = 0; s < 64; ++s) c += (cpt[r*64 + s] != 0);
    len[r] = c > 1 ? c : 1;
  }
}

// ---- embed GEMM: mem[sent][b][s][h] = bf16(elu(emb_table[cpt] @ W_eh^T + b_eh)) ----
// grid = (98304/64) * (512/64) = 12288 blocks, 256 threads, 64x64 tile, BK=32
__global__ __launch_bounds__(256) void embed_gemm(
    const int* __restrict__ cpt, const float* __restrict__ table,
    const float* __restrict__ Weh, const float* __restrict__ beh,
    bf16_t* __restrict__ mem)
{
  __shared__ unsigned short A_lds[64][40];  // pad 32->40 bf16 to break bank conflicts
  __shared__ unsigned short B_lds[64][40];
  const int bid = blockIdx.x;
  const int M0 = (bid >> 3) * 64;
  const int N0 = (bid & 7) * 64;
  const int tid = threadIdx.x, lane = tid & 63, w = tid >> 6;
  const int l15 = lane & 15, quad = lane >> 4;
  const int srow = tid >> 2;            // 0..63
  const int koff = (tid & 3) * 8;       // 0,8,16,24
  const int tok = cpt[M0 + srow];
  const float* arow = table + (size_t)tok * 512;
  const float* brow = Weh + (size_t)(N0 + srow) * 512;

  f32x4 acc0 = {0,0,0,0}, acc1 = {0,0,0,0}, acc2 = {0,0,0,0}, acc3 = {0,0,0,0};
  for (int kt = 0; kt < 16; ++kt) {
    const int k0 = kt * 32;
    float4 alo = *(const float4*)(arow + k0 + koff);
    float4 ahi = *(const float4*)(arow + k0 + koff + 4);
    float4 blo = *(const float4*)(brow + k0 + koff);
    float4 bhi = *(const float4*)(brow + k0 + koff + 4);
    __syncthreads();
    *(bf16x8*)(&A_lds[srow][koff]) = cvt8(alo, ahi);
    *(bf16x8*)(&B_lds[srow][koff]) = cvt8(blo, bhi);
    __syncthreads();
    const int kq = quad * 8;
    bf16x8 bfr = *(const bf16x8*)(&B_lds[16*w + l15][kq]);
    bf16x8 a0 = *(const bf16x8*)(&A_lds[l15][kq]);
    bf16x8 a1 = *(const bf16x8*)(&A_lds[16 + l15][kq]);
    bf16x8 a2 = *(const bf16x8*)(&A_lds[32 + l15][kq]);
    bf16x8 a3 = *(const bf16x8*)(&A_lds[48 + l15][kq]);
    acc0 = MFMA16(a0, bfr, acc0);
    acc1 = MFMA16(a1, bfr, acc1);
    acc2 = MFMA16(a2, bfr, acc2);
    acc3 = MFMA16(a3, bfr, acc3);
  }
  const int n = N0 + 16*w + l15;
  const float bias = beh[n];
  f32x4 accs[4] = {acc0, acc1, acc2, acc3};
  #pragma unroll
  for (int mt = 0; mt < 4; ++mt) {
    #pragma unroll
    for (int r = 0; r < 4; ++r) {
      int m = M0 + mt*16 + quad*4 + r;          // global token row
      float v = accs[mt][r] + bias;
      v = v > 0.f ? v : expm1f(v);
      int s = m & 63, nrow = m >> 6;
      int sent = nrow % 48, b = nrow / 48;
      mem[(((size_t)(sent*32 + b))*64 + s)*512 + n] = (__bf16)v;
    }
  }
}

// ---- persistent scan: 32 blocks (co-resident), 4 barrier phases / step ----
__global__ __launch_bounds__(256) void scan_kernel(
    const bf16_t* __restrict__ mem, const int* __restrict__ lengths,
    const bf16_t* __restrict__ WA, const bf16_t* __restrict__ Wout, const bf16_t* __restrict__ Wih,
    const float* __restrict__ b_ih, const float* __restrict__ b_hh,
    float* __restrict__ q, float* __restrict__ gh,
    float* __restrict__ h, bf16_t* __restrict__ hbf,
    bf16_t* __restrict__ cbf, bf16_t* __restrict__ xbf,
    unsigned* __restrict__ bar, float* __restrict__ out)
{
  // smem map: [0,33280) h_lds (A,C) / x_lds (D): 32 rows * 1040B (512+8 bf16 pad)
  //           [33280,...) stage scratch: B: q_lds(2048)+sc(256)+al(256)
  //                                      C: c_lds 32*528=16896 ; xb_lds @50176 (2176)
  //                                      D: gi_lds 6*272*4=6528
  __shared__ __align__(16) unsigned char smem[52352];
  unsigned short* h_lds = (unsigned short*)smem;
  unsigned short* x_lds = (unsigned short*)smem;
  float* q_lds  = (float*)(smem + 33280);
  float* sc_lds = (float*)(smem + 35328);
  float* al_lds = (float*)(smem + 35584);
  unsigned short* c_lds = (unsigned short*)(smem + 33280);
  float* xb_lds = (float*)(smem + 50176);
  float* gi_lds = (float*)(smem + 33280);

  const int g = blockIdx.x, tid = threadIdx.x, lane = tid & 63, w = tid >> 6;
  const int quad = lane >> 4, l15 = lane & 15;
  int phase = 0;

  for (int i = 0; i < 48; ++i) {
    // ================= stage A: q = h W_in^T ; gh = h W_hh^T + b_hh ==========
    for (int it = 0; it < 16; ++it) {
      int chunk = tid + 256*it;            // 4096 u64 chunks of hbf [32][512]
      int row = chunk >> 7, cc = chunk & 127;
      unsigned long long v = ld_a64(hbf + row*512 + cc*4);
      *(unsigned long long*)((char*)h_lds + row*1040 + cc*8) = v;
    }
    __syncthreads();
    {
      f32x4 acc0 = {0,0,0,0}, acc1 = {0,0,0,0};
      const int nrow = 64*g + 16*w + l15;          // 0..2047 rows of [W_in;W_hh]
      const bf16_t* wrow = WA + (size_t)nrow * 512;
      #pragma unroll
      for (int kt = 0; kt < 16; ++kt) {
        const int k = kt*32 + quad*8;
        bf16x8 bfr = *(const bf16x8*)(wrow + k);
        bf16x8 a0 = *(const bf16x8*)((char*)h_lds + l15*1040 + k*2);
        bf16x8 a1 = *(const bf16x8*)((char*)h_lds + (16 + l15)*1040 + k*2);
        acc0 = MFMA16(a0, bfr, acc0);
        acc1 = MFMA16(a1, bfr, acc1);
      }
      const float bias = (nrow >= 512) ? b_hh[nrow - 512] : 0.f;
      #pragma unroll
      for (int r = 0; r < 4; ++r) {
        int b0 = quad*4 + r;
        float v0 = acc0[r] + bias, v1 = acc1[r] + bias;
        if (nrow < 512) {
          st_a32(q + b0*512 + nrow,        __builtin_bit_cast(unsigned, v0));
          st_a32(q + (b0+16)*512 + nrow,   __builtin_bit_cast(unsigned, v1));
        } else {
          st_a32(gh + b0*1536 + nrow-512,      __builtin_bit_cast(unsigned, v0));
          st_a32(gh + (b0+16)*1536 + nrow-512, __builtin_bit_cast(unsigned, v1));
        }
      }
    }
    gbar(bar, ++phase * 32);

    // ================= stage B: attention for batch b = g ====================
    {
      for (int it = 0; it < 2; ++it) {
        int idx = tid + 256*it;
        unsigned v = ld_a32(q + g*512 + idx);
        q_lds[idx] = __builtin_bit_cast(float, v);
      }
      __syncthreads();
      const bf16_t* mrow = mem + ((size_t)(i*32 + g)) * 64 * 512;
      {
        const int s = tid >> 2, p = tid & 3;
        const uint4* mp = (const uint4*)(mrow + s*512 + p*128);
        const float* qp = q_lds + p*128;
        float sum = 0.f;
        #pragma unroll
        for (int it = 0; it < 16; ++it) {
          uint4 u = mp[it];
          float2 f0 = bf2f(u.x), f1 = bf2f(u.y), f2 = bf2f(u.z), f3 = bf2f(u.w);
          const float* qq = qp + it*8;
          sum += f0.x*qq[0] + f0.y*qq[1] + f1.x*qq[2] + f1.y*qq[3]
               + f2.x*qq[4] + f2.y*qq[5] + f3.x*qq[6] + f3.y*qq[7];
        }
        sum += __shfl_xor(sum, 1);
        sum += __shfl_xor(sum, 2);
        if (p == 0) {
          int len = lengths[g*48 + i];
          sc_lds[s] = (s < len) ? sum : -1e30f;
        }
      }
      __syncthreads();
      if (tid < 64) {
        float v = sc_lds[tid];
        float mx = v;
        #pragma unroll
        for (int o = 32; o; o >>= 1) mx = fmaxf(mx, __shfl_xor(mx, o));
        float e = expf(v - mx);
        float sm = e;
        #pragma unroll
        for (int o = 32; o; o >>= 1) sm += __shfl_xor(sm, o);
        al_lds[tid] = e / sm;
      }
      __syncthreads();
      {
        const int d0 = tid * 2;
        float c0 = 0.f, c1 = 0.f;
        for (int s2 = 0; s2 < 64; ++s2) {
          unsigned u = *(const unsigned*)(mrow + s2*512 + d0);
          float2 f = bf2f(u);
          float a = al_lds[s2];
          c0 += a * f.x; c1 += a * f.y;
        }
        st_a32(cbf + g*512 + d0, pack_bf2(c0, c1));
      }
    }
    gbar(bar, ++phase * 32);

    // ================= stage C: x = tanh([c;h] W_out^T) ======================
    {
      f32x4 acc = {0,0,0,0};
      const int nrow = 16*g + l15;
      const bf16_t* wrow = Wout + (size_t)nrow * 1024;
      for (int kh = 0; kh < 2; ++kh) {
        for (int it = 0; it < 8; ++it) {
          int cid = tid + 256*it;         // 2048 u64 chunks of cbf half
          int row = cid >> 6, cc = cid & 63;
          unsigned long long v = ld_a64(cbf + row*512 + kh*256 + cc*4);
          *(unsigned long long*)((char*)c_lds + row*528 + cc*8) = v;
        }
        __syncthreads();
        if (w < 2) {
          #pragma unroll
          for (int kt = 0; kt < 8; ++kt) {
            const int kl = kt*32 + quad*8;
            bf16x8 bfr = *(const bf16x8*)(wrow + kh*256 + kl);
            bf16x8 af  = *(const bf16x8*)((char*)c_lds + (16*w + l15)*528 + kl*2);
            acc = MFMA16(af, bfr, acc);
          }
        }
        __syncthreads();
      }
      if (w < 2) {
        #pragma unroll
        for (int kt = 0; kt < 16; ++kt) {
          const int k = kt*32 + quad*8;
          bf16x8 bfr = *(const bf16x8*)(wrow + 512 + k);
          bf16x8 af  = *(const bf16x8*)((char*)h_lds + (16*w + l15)*1040 + k*2);
          acc = MFMA16(af, bfr, acc);
        }
        #pragma unroll
        for (int r = 0; r < 4; ++r)
          xb_lds[w*272 + l15*17 + quad*4 + r] = acc[r];
      }
      __syncthreads();
      {
        const int b = tid >> 3, np = tid & 7;
        const int mt = b >> 4, ml = b & 15;
        float v0 = tanhf(xb_lds[mt*272 + (2*np)*17 + ml]);
        float v1 = tanhf(xb_lds[mt*272 + (2*np+1)*17 + ml]);
        st_a32(xbf + b*512 + 16*g + 2*np, pack_bf2(v0, v1));
      }
    }
    gbar(bar, ++phase * 32);

    // ================= stage D: gi = x W_ih^T + b_ih ; GRU combine ===========
    {
      for (int it = 0; it < 16; ++it) {
        int chunk = tid + 256*it;
        int row = chunk >> 7, cc = chunk & 127;
        unsigned long long v = ld_a64(xbf + row*512 + cc*4);
        *(unsigned long long*)((char*)x_lds + row*1040 + cc*8) = v;
      }
      __syncthreads();
      #pragma unroll
      for (int tt = 0; tt < 2; ++tt) {
        const int t = w + 4*tt;
        if (t < 6) {
          const int nt = t % 3, mt = t / 3;   // t = mt*3 + nt
          f32x4 acc = {0,0,0,0};
          const int nrow = nt*512 + 16*g + l15;
          const bf16_t* wrow = Wih + (size_t)nrow * 512;
          #pragma unroll
          for (int kt = 0; kt < 16; ++kt) {
            const int k = kt*32 + quad*8;
            bf16x8 bfr = *(const bf16x8*)(wrow + k);
            bf16x8 af  = *(const bf16x8*)((char*)x_lds + (16*mt + l15)*1040 + k*2);
            acc = MFMA16(af, bfr, acc);
          }
          #pragma unroll
          for (int r = 0; r < 4; ++r)
            gi_lds[t*272 + l15*17 + quad*4 + r] = acc[r];
        }
      }
      __syncthreads();
      {
        const int b = tid >> 3, dlp = tid & 7;
        const int mt = b >> 4, ml = b & 15;
        const int d0 = 16*g + 2*dlp;
        unsigned long long ur = ld_a64(gh + b*1536 + d0);
        unsigned long long uz = ld_a64(gh + b*1536 + 512 + d0);
        unsigned long long un = ld_a64(gh + b*1536 + 1024 + d0);
        unsigned long long uh = ld_a64(h + b*512 + d0);
        float hr0 = __builtin_bit_cast(float, (unsigned)(ur & 0xffffffffu));
        float hr1 = __builtin_bit_cast(float, (unsigned)(ur >> 32));
        float hz0 = __builtin_bit_cast(float, (unsigned)(uz & 0xffffffffu));
        float hz1 = __builtin_bit_cast(float, (unsigned)(uz >> 32));
        float hn0 = __builtin_bit_cast(float, (unsigned)(un & 0xffffffffu));
        float hn1 = __builtin_bit_cast(float, (unsigned)(un >> 32));
        float ho0 = __builtin_bit_cast(float, (unsigned)(uh & 0xffffffffu));
        float ho1 = __builtin_bit_cast(float, (unsigned)(uh >> 32));
        float res[2];
        #pragma unroll
        for (int e = 0; e < 2; ++e) {
          int dl = 2*dlp + e;
          float ir = gi_lds[(mt*3+0)*272 + dl*17 + ml] + b_ih[16*g + dl];
          float iz = gi_lds[(mt*3+1)*272 + dl*17 + ml] + b_ih[512 + 16*g + dl];
          float in = gi_lds[(mt*3+2)*272 + dl*17 + ml] + b_ih[1024 + 16*g + dl];
          float hr = e ? hr1 : hr0, hz = e ? hz1 : hz0, hn = e ? hn1 : hn0, ho = e ? ho1 : ho0;
          float rr = 1.f / (1.f + expf(-(ir + hr)));
          float zz = 1.f / (1.f + expf(-(iz + hz)));
          float nn = tanhf(in + rr * hn);
          res[e] = (1.f - zz) * nn + zz * ho;
        }
        if (i == 47) {
          out[b*512 + d0]     = res[0];
          out[b*512 + d0 + 1] = res[1];
        } else {
          unsigned long long pk = (unsigned long long)__builtin_bit_cast(unsigned, res[0])
                                | ((unsigned long long)__builtin_bit_cast(unsigned, res[1]) << 32);
          st_a64(h + b*512 + d0, pk);
          st_a32(hbf + b*512 + d0, pack_bf2(res[0], res[1]));
        }
      }
    }
    gbar(bar, ++phase * 32);
  }
}

// ---------------------------------------------------------------------------
extern "C" void kernel_launch(void* const* d_in, const int* in_sizes, int n_in,
                              void* d_out, int out_size, void* d_ws, size_t ws_size,
                              hipStream_t stream) {
  const int*   cpt   = (const int*)d_in[0];
  const float* table = (const float*)d_in[2];
  const float* Weh   = (const float*)d_in[3];
  const float* beh   = (const float*)d_in[4];
  const float* h0    = (const float*)d_in[5];
  const float* Win   = (const float*)d_in[6];
  const float* Wout  = (const float*)d_in[7];
  const float* Wih   = (const float*)d_in[8];
  const float* Whh   = (const float*)d_in[9];
  const float* bih   = (const float*)d_in[10];
  const float* bhh   = (const float*)d_in[11];

  if (ws_size < WS_NEED) return;  // cannot run without workspace

  char* ws = (char*)d_ws;
  bf16_t* mem   = (bf16_t*)(ws);
  bf16_t* WA    = (bf16_t*)(ws + OFF_WA);
  bf16_t* WoutB = (bf16_t*)(ws + OFF_WOUT);
  bf16_t* WihB  = (bf16_t*)(ws + OFF_WIH);
  int*    len   = (int*)(ws + OFF_LEN);
  float*  h     = (float*)(ws + OFF_H);
  bf16_t* hbf   = (bf16_t*)(ws + OFF_HBF);
  float*  q     = (float*)(ws + OFF_Q);
  float*  gh    = (float*)(ws + OFF_GH);
  bf16_t* cbf   = (bf16_t*)(ws + OFF_CBF);
  bf16_t* xbf   = (bf16_t*)(ws + OFF_XBF);
  unsigned* bar = (unsigned*)(ws + OFF_BAR);

  hipMemsetAsync(bar, 0, 256, stream);
  prep_weights<<<9216, 256, 0, stream>>>(Win, Whh, Wout, Wih, WA, WoutB, WihB);
  h_init<<<64, 256, 0, stream>>>(h0, h, hbf);
  lengths_kernel<<<6, 256, 0, stream>>>(cpt, len);
  embed_gemm<<<12288, 256, 0, stream>>>(cpt, table, Weh, beh, mem);
  scan_kernel<<<32, 256, 0, stream>>>(mem, len, WA, WoutB, WihB, bih, bhh,
                                      q, gh, h, hbf, cbf, xbf, bar, (float*)d_out);
}

// Round 2
// 2031.339 us; speedup vs baseline: 1.0564x; 1.0564x over previous
//
#include <hip/hip_runtime.h>
#include <hip/hip_bf16.h>
#include <stdint.h>

// ---------------------------------------------------------------------------
// GraphEncoder: emb-lookup -> elu(emb@W_eh^T+b) -> 48-step attention-GRU scan
// Round 2: all-relaxed grid barrier (no agent-scope acquire/release cache
//          maintenance). Cross-block data stays on sc1 relaxed atomics, which
//          are coherent at L3 by construction; __syncthreads() drains vmcnt
//          before the counter bump so ordering holds without fences.
// ---------------------------------------------------------------------------

typedef __bf16 bf16_t;
typedef __bf16 bf16x8 __attribute__((ext_vector_type(8)));
typedef float  f32x4  __attribute__((ext_vector_type(4)));

#define MFMA16(a,b,c) __builtin_amdgcn_mfma_f32_16x16x32_bf16((a),(b),(c),0,0,0)

// ---- workspace layout (bytes) ----
static constexpr size_t SZ_MEM   = 48ull*32*64*512*2;      // 100,663,296 bf16 mem[sent][b][s][h]
static constexpr size_t OFF_WA   = SZ_MEM;                 // [W_in;W_hh] bf16 [2048][512]
static constexpr size_t SZ_WA    = 2048ull*512*2;
static constexpr size_t OFF_WOUT = OFF_WA + SZ_WA;         // W_out bf16 [512][1024]
static constexpr size_t SZ_WOUT  = 512ull*1024*2;
static constexpr size_t OFF_WIH  = OFF_WOUT + SZ_WOUT;     // W_ih bf16 [1536][512]
static constexpr size_t SZ_WIH   = 1536ull*512*2;
static constexpr size_t OFF_LEN  = OFF_WIH + SZ_WIH;       // int[1536]
static constexpr size_t OFF_H    = OFF_LEN + 8192;         // f32 [32][512]
static constexpr size_t OFF_HBF  = OFF_H + 65536;          // bf16 [32][512]
static constexpr size_t OFF_Q    = OFF_HBF + 32768;        // f32 [32][512]
static constexpr size_t OFF_GH   = OFF_Q + 65536;          // f32 [32][1536]
static constexpr size_t OFF_CBF  = OFF_GH + 196608;        // bf16 [32][512]
static constexpr size_t OFF_XBF  = OFF_CBF + 32768;        // bf16 [32][512]
static constexpr size_t OFF_BAR  = OFF_XBF + 32768;        // barrier counter
static constexpr size_t WS_NEED  = OFF_BAR + 256;

// ---- helpers ----
__device__ __forceinline__ unsigned ld_a32(const void* p) {
  return __hip_atomic_load((const unsigned*)p, __ATOMIC_RELAXED, __HIP_MEMORY_SCOPE_AGENT);
}
__device__ __forceinline__ unsigned long long ld_a64(const void* p) {
  return __hip_atomic_load((const unsigned long long*)p, __ATOMIC_RELAXED, __HIP_MEMORY_SCOPE_AGENT);
}
__device__ __forceinline__ void st_a32(void* p, unsigned v) {
  __hip_atomic_store((unsigned*)p, v, __ATOMIC_RELAXED, __HIP_MEMORY_SCOPE_AGENT);
}
__device__ __forceinline__ void st_a64(void* p, unsigned long long v) {
  __hip_atomic_store((unsigned long long*)p, v, __ATOMIC_RELAXED, __HIP_MEMORY_SCOPE_AGENT);
}
__device__ __forceinline__ float2 bf2f(unsigned u) {
  float2 r;
  unsigned lo = u << 16, hi = u & 0xffff0000u;
  r.x = __builtin_bit_cast(float, lo);
  r.y = __builtin_bit_cast(float, hi);
  return r;
}
__device__ __forceinline__ unsigned pack_bf2(float a, float b) {
  __bf16 ba = (__bf16)a, bb = (__bf16)b;
  unsigned short ua = __builtin_bit_cast(unsigned short, ba);
  unsigned short ub = __builtin_bit_cast(unsigned short, bb);
  return (unsigned)ua | ((unsigned)ub << 16);
}
__device__ __forceinline__ bf16x8 cvt8(float4 lo, float4 hi) {
  bf16x8 v;
  v[0]=(__bf16)lo.x; v[1]=(__bf16)lo.y; v[2]=(__bf16)lo.z; v[3]=(__bf16)lo.w;
  v[4]=(__bf16)hi.x; v[5]=(__bf16)hi.y; v[6]=(__bf16)hi.z; v[7]=(__bf16)hi.w;
  return v;
}
// monotonic-counter grid barrier, ALL-RELAXED (no L2 wb/inv cache maintenance).
// Safe because: (1) __syncthreads() emits s_waitcnt vmcnt(0) before s_barrier,
// so every wave's sc1 data stores are at the coherence point before thread 0
// bumps the counter; (2) all cross-block data uses sc1 relaxed atomics, so no
// stale L1/L2 copies exist to invalidate.
__device__ __forceinline__ void gbar(unsigned* cnt, int target) {
  __syncthreads();
  if (threadIdx.x == 0) {
    __hip_atomic_fetch_add(cnt, 1u, __ATOMIC_RELAXED, __HIP_MEMORY_SCOPE_AGENT);
    while ((int)__hip_atomic_load(cnt, __ATOMIC_RELAXED, __HIP_MEMORY_SCOPE_AGENT) < target) {
      __builtin_amdgcn_s_sleep(1);
    }
  }
  __syncthreads();
}

// ---- prep: convert weights to bf16 ----
__global__ __launch_bounds__(256) void prep_weights(
    const float* __restrict__ Win, const float* __restrict__ Whh,
    const float* __restrict__ Wout, const float* __restrict__ Wih,
    bf16_t* __restrict__ WA, bf16_t* __restrict__ WoutB, bf16_t* __restrict__ WihB)
{
  int idx = blockIdx.x * 256 + threadIdx.x;
  if (idx < 262144)        WA[idx]            = (__bf16)Win[idx];
  else if (idx < 1048576)  WA[idx]            = (__bf16)Whh[idx - 262144];
  else if (idx < 1572864)  WoutB[idx-1048576] = (__bf16)Wout[idx - 1048576];
  else if (idx < 2359296)  WihB[idx-1572864]  = (__bf16)Wih[idx - 1572864];
}

__global__ __launch_bounds__(256) void h_init(
    const float* __restrict__ h0, float* __restrict__ h, bf16_t* __restrict__ hbf)
{
  int idx = blockIdx.x * 256 + threadIdx.x;   // 16384
  float v = h0[idx & 511];
  h[idx] = v;
  hbf[idx] = (__bf16)v;
}

__global__ __launch_bounds__(256) void lengths_kernel(
    const int* __restrict__ cpt, int* __restrict__ len)
{
  int r = blockIdx.x * 256 + threadIdx.x;
  if (r < 1536) {
    int c = 0;
    for (int s = 0; s < 64; ++s) c += (cpt[r*64 + s] != 0);
    len[r] = c > 1 ? c : 1;
  }
}

// ---- embed GEMM: mem[sent][b][s][h] = bf16(elu(emb_table[cpt] @ W_eh^T + b_eh)) ----
// grid = (98304/64) * (512/64) = 12288 blocks, 256 threads, 64x64 tile, BK=32
__global__ __launch_bounds__(256) void embed_gemm(
    const int* __restrict__ cpt, const float* __restrict__ table,
    const float* __restrict__ Weh, const float* __restrict__ beh,
    bf16_t* __restrict__ mem)
{
  __shared__ unsigned short A_lds[64][40];  // pad 32->40 bf16 to break bank conflicts
  __shared__ unsigned short B_lds[64][40];
  const int bid = blockIdx.x;
  const int M0 = (bid >> 3) * 64;
  const int N0 = (bid & 7) * 64;
  const int tid = threadIdx.x, lane = tid & 63, w = tid >> 6;
  const int l15 = lane & 15, quad = lane >> 4;
  const int srow = tid >> 2;            // 0..63
  const int koff = (tid & 3) * 8;       // 0,8,16,24
  const int tok = cpt[M0 + srow];
  const float* arow = table + (size_t)tok * 512;
  const float* brow = Weh + (size_t)(N0 + srow) * 512;

  f32x4 acc0 = {0,0,0,0}, acc1 = {0,0,0,0}, acc2 = {0,0,0,0}, acc3 = {0,0,0,0};
  for (int kt = 0; kt < 16; ++kt) {
    const int k0 = kt * 32;
    float4 alo = *(const float4*)(arow + k0 + koff);
    float4 ahi = *(const float4*)(arow + k0 + koff + 4);
    float4 blo = *(const float4*)(brow + k0 + koff);
    float4 bhi = *(const float4*)(brow + k0 + koff + 4);
    __syncthreads();
    *(bf16x8*)(&A_lds[srow][koff]) = cvt8(alo, ahi);
    *(bf16x8*)(&B_lds[srow][koff]) = cvt8(blo, bhi);
    __syncthreads();
    const int kq = quad * 8;
    bf16x8 bfr = *(const bf16x8*)(&B_lds[16*w + l15][kq]);
    bf16x8 a0 = *(const bf16x8*)(&A_lds[l15][kq]);
    bf16x8 a1 = *(const bf16x8*)(&A_lds[16 + l15][kq]);
    bf16x8 a2 = *(const bf16x8*)(&A_lds[32 + l15][kq]);
    bf16x8 a3 = *(const bf16x8*)(&A_lds[48 + l15][kq]);
    acc0 = MFMA16(a0, bfr, acc0);
    acc1 = MFMA16(a1, bfr, acc1);
    acc2 = MFMA16(a2, bfr, acc2);
    acc3 = MFMA16(a3, bfr, acc3);
  }
  const int n = N0 + 16*w + l15;
  const float bias = beh[n];
  f32x4 accs[4] = {acc0, acc1, acc2, acc3};
  #pragma unroll
  for (int mt = 0; mt < 4; ++mt) {
    #pragma unroll
    for (int r = 0; r < 4; ++r) {
      int m = M0 + mt*16 + quad*4 + r;          // global token row
      float v = accs[mt][r] + bias;
      v = v > 0.f ? v : expm1f(v);
      int s = m & 63, nrow = m >> 6;
      int sent = nrow % 48, b = nrow / 48;
      mem[(((size_t)(sent*32 + b))*64 + s)*512 + n] = (__bf16)v;
    }
  }
}

// ---- persistent scan: 32 blocks (co-resident), 4 barrier phases / step ----
__global__ __launch_bounds__(256) void scan_kernel(
    const bf16_t* __restrict__ mem, const int* __restrict__ lengths,
    const bf16_t* __restrict__ WA, const bf16_t* __restrict__ Wout, const bf16_t* __restrict__ Wih,
    const float* __restrict__ b_ih, const float* __restrict__ b_hh,
    float* __restrict__ q, float* __restrict__ gh,
    float* __restrict__ h, bf16_t* __restrict__ hbf,
    bf16_t* __restrict__ cbf, bf16_t* __restrict__ xbf,
    unsigned* __restrict__ bar, float* __restrict__ out)
{
  // smem map: [0,33280) h_lds (A,C) / x_lds (D): 32 rows * 1040B (512+8 bf16 pad)
  //           [33280,...) stage scratch: B: q_lds(2048)+sc(256)+al(256)
  //                                      C: c_lds 32*528=16896 ; xb_lds @50176 (2176)
  //                                      D: gi_lds 6*272*4=6528
  __shared__ __align__(16) unsigned char smem[52352];
  unsigned short* h_lds = (unsigned short*)smem;
  unsigned short* x_lds = (unsigned short*)smem;
  float* q_lds  = (float*)(smem + 33280);
  float* sc_lds = (float*)(smem + 35328);
  float* al_lds = (float*)(smem + 35584);
  unsigned short* c_lds = (unsigned short*)(smem + 33280);
  float* xb_lds = (float*)(smem + 50176);
  float* gi_lds = (float*)(smem + 33280);

  const int g = blockIdx.x, tid = threadIdx.x, lane = tid & 63, w = tid >> 6;
  const int quad = lane >> 4, l15 = lane & 15;
  int phase = 0;

  for (int i = 0; i < 48; ++i) {
    // ================= stage A: q = h W_in^T ; gh = h W_hh^T + b_hh ==========
    for (int it = 0; it < 16; ++it) {
      int chunk = tid + 256*it;            // 4096 u64 chunks of hbf [32][512]
      int row = chunk >> 7, cc = chunk & 127;
      unsigned long long v = ld_a64(hbf + row*512 + cc*4);
      *(unsigned long long*)((char*)h_lds + row*1040 + cc*8) = v;
    }
    __syncthreads();
    {
      f32x4 acc0 = {0,0,0,0}, acc1 = {0,0,0,0};
      const int nrow = 64*g + 16*w + l15;          // 0..2047 rows of [W_in;W_hh]
      const bf16_t* wrow = WA + (size_t)nrow * 512;
      #pragma unroll
      for (int kt = 0; kt < 16; ++kt) {
        const int k = kt*32 + quad*8;
        bf16x8 bfr = *(const bf16x8*)(wrow + k);
        bf16x8 a0 = *(const bf16x8*)((char*)h_lds + l15*1040 + k*2);
        bf16x8 a1 = *(const bf16x8*)((char*)h_lds + (16 + l15)*1040 + k*2);
        acc0 = MFMA16(a0, bfr, acc0);
        acc1 = MFMA16(a1, bfr, acc1);
      }
      const float bias = (nrow >= 512) ? b_hh[nrow - 512] : 0.f;
      #pragma unroll
      for (int r = 0; r < 4; ++r) {
        int b0 = quad*4 + r;
        float v0 = acc0[r] + bias, v1 = acc1[r] + bias;
        if (nrow < 512) {
          st_a32(q + b0*512 + nrow,        __builtin_bit_cast(unsigned, v0));
          st_a32(q + (b0+16)*512 + nrow,   __builtin_bit_cast(unsigned, v1));
        } else {
          st_a32(gh + b0*1536 + nrow-512,      __builtin_bit_cast(unsigned, v0));
          st_a32(gh + (b0+16)*1536 + nrow-512, __builtin_bit_cast(unsigned, v1));
        }
      }
    }
    gbar(bar, ++phase * 32);

    // ================= stage B: attention for batch b = g ====================
    {
      for (int it = 0; it < 2; ++it) {
        int idx = tid + 256*it;
        unsigned v = ld_a32(q + g*512 + idx);
        q_lds[idx] = __builtin_bit_cast(float, v);
      }
      __syncthreads();
      const bf16_t* mrow = mem + ((size_t)(i*32 + g)) * 64 * 512;
      {
        const int s = tid >> 2, p = tid & 3;
        const uint4* mp = (const uint4*)(mrow + s*512 + p*128);
        const float* qp = q_lds + p*128;
        float sum = 0.f;
        #pragma unroll
        for (int it = 0; it < 16; ++it) {
          uint4 u = mp[it];
          float2 f0 = bf2f(u.x), f1 = bf2f(u.y), f2 = bf2f(u.z), f3 = bf2f(u.w);
          const float* qq = qp + it*8;
          sum += f0.x*qq[0] + f0.y*qq[1] + f1.x*qq[2] + f1.y*qq[3]
               + f2.x*qq[4] + f2.y*qq[5] + f3.x*qq[6] + f3.y*qq[7];
        }
        sum += __shfl_xor(sum, 1);
        sum += __shfl_xor(sum, 2);
        if (p == 0) {
          int len = lengths[g*48 + i];
          sc_lds[s] = (s < len) ? sum : -1e30f;
        }
      }
      __syncthreads();
      if (tid < 64) {
        float v = sc_lds[tid];
        float mx = v;
        #pragma unroll
        for (int o = 32; o; o >>= 1) mx = fmaxf(mx, __shfl_xor(mx, o));
        float e = expf(v - mx);
        float sm = e;
        #pragma unroll
        for (int o = 32; o; o >>= 1) sm += __shfl_xor(sm, o);
        al_lds[tid] = e / sm;
      }
      __syncthreads();
      {
        const int d0 = tid * 2;
        float c0 = 0.f, c1 = 0.f;
        for (int s2 = 0; s2 < 64; ++s2) {
          unsigned u = *(const unsigned*)(mrow + s2*512 + d0);
          float2 f = bf2f(u);
          float a = al_lds[s2];
          c0 += a * f.x; c1 += a * f.y;
        }
        st_a32(cbf + g*512 + d0, pack_bf2(c0, c1));
      }
    }
    gbar(bar, ++phase * 32);

    // ================= stage C: x = tanh([c;h] W_out^T) ======================
    {
      f32x4 acc = {0,0,0,0};
      const int nrow = 16*g + l15;
      const bf16_t* wrow = Wout + (size_t)nrow * 1024;
      for (int kh = 0; kh < 2; ++kh) {
        for (int it = 0; it < 8; ++it) {
          int cid = tid + 256*it;         // 2048 u64 chunks of cbf half
          int row = cid >> 6, cc = cid & 63;
          unsigned long long v = ld_a64(cbf + row*512 + kh*256 + cc*4);
          *(unsigned long long*)((char*)c_lds + row*528 + cc*8) = v;
        }
        __syncthreads();
        if (w < 2) {
          #pragma unroll
          for (int kt = 0; kt < 8; ++kt) {
            const int kl = kt*32 + quad*8;
            bf16x8 bfr = *(const bf16x8*)(wrow + kh*256 + kl);
            bf16x8 af  = *(const bf16x8*)((char*)c_lds + (16*w + l15)*528 + kl*2);
            acc = MFMA16(af, bfr, acc);
          }
        }
        __syncthreads();
      }
      if (w < 2) {
        #pragma unroll
        for (int kt = 0; kt < 16; ++kt) {
          const int k = kt*32 + quad*8;
          bf16x8 bfr = *(const bf16x8*)(wrow + 512 + k);
          bf16x8 af  = *(const bf16x8*)((char*)h_lds + (16*w + l15)*1040 + k*2);
          acc = MFMA16(af, bfr, acc);
        }
        #pragma unroll
        for (int r = 0; r < 4; ++r)
          xb_lds[w*272 + l15*17 + quad*4 + r] = acc[r];
      }
      __syncthreads();
      {
        const int b = tid >> 3, np = tid & 7;
        const int mt = b >> 4, ml = b & 15;
        float v0 = tanhf(xb_lds[mt*272 + (2*np)*17 + ml]);
        float v1 = tanhf(xb_lds[mt*272 + (2*np+1)*17 + ml]);
        st_a32(xbf + b*512 + 16*g + 2*np, pack_bf2(v0, v1));
      }
    }
    gbar(bar, ++phase * 32);

    // ================= stage D: gi = x W_ih^T + b_ih ; GRU combine ===========
    {
      for (int it = 0; it < 16; ++it) {
        int chunk = tid + 256*it;
        int row = chunk >> 7, cc = chunk & 127;
        unsigned long long v = ld_a64(xbf + row*512 + cc*4);
        *(unsigned long long*)((char*)x_lds + row*1040 + cc*8) = v;
      }
      __syncthreads();
      #pragma unroll
      for (int tt = 0; tt < 2; ++tt) {
        const int t = w + 4*tt;
        if (t < 6) {
          const int nt = t % 3, mt = t / 3;   // t = mt*3 + nt
          f32x4 acc = {0,0,0,0};
          const int nrow = nt*512 + 16*g + l15;
          const bf16_t* wrow = Wih + (size_t)nrow * 512;
          #pragma unroll
          for (int kt = 0; kt < 16; ++kt) {
            const int k = kt*32 + quad*8;
            bf16x8 bfr = *(const bf16x8*)(wrow + k);
            bf16x8 af  = *(const bf16x8*)((char*)x_lds + (16*mt + l15)*1040 + k*2);
            acc = MFMA16(af, bfr, acc);
          }
          #pragma unroll
          for (int r = 0; r < 4; ++r)
            gi_lds[t*272 + l15*17 + quad*4 + r] = acc[r];
        }
      }
      __syncthreads();
      {
        const int b = tid >> 3, dlp = tid & 7;
        const int mt = b >> 4, ml = b & 15;
        const int d0 = 16*g + 2*dlp;
        unsigned long long ur = ld_a64(gh + b*1536 + d0);
        unsigned long long uz = ld_a64(gh + b*1536 + 512 + d0);
        unsigned long long un = ld_a64(gh + b*1536 + 1024 + d0);
        unsigned long long uh = ld_a64(h + b*512 + d0);
        float hr0 = __builtin_bit_cast(float, (unsigned)(ur & 0xffffffffu));
        float hr1 = __builtin_bit_cast(float, (unsigned)(ur >> 32));
        float hz0 = __builtin_bit_cast(float, (unsigned)(uz & 0xffffffffu));
        float hz1 = __builtin_bit_cast(float, (unsigned)(uz >> 32));
        float hn0 = __builtin_bit_cast(float, (unsigned)(un & 0xffffffffu));
        float hn1 = __builtin_bit_cast(float, (unsigned)(un >> 32));
        float ho0 = __builtin_bit_cast(float, (unsigned)(uh & 0xffffffffu));
        float ho1 = __builtin_bit_cast(float, (unsigned)(uh >> 32));
        float res[2];
        #pragma unroll
        for (int e = 0; e < 2; ++e) {
          int dl = 2*dlp + e;
          float ir = gi_lds[(mt*3+0)*272 + dl*17 + ml] + b_ih[16*g + dl];
          float iz = gi_lds[(mt*3+1)*272 + dl*17 + ml] + b_ih[512 + 16*g + dl];
          float in = gi_lds[(mt*3+2)*272 + dl*17 + ml] + b_ih[1024 + 16*g + dl];
          float hr = e ? hr1 : hr0, hz = e ? hz1 : hz0, hn = e ? hn1 : hn0, ho = e ? ho1 : ho0;
          float rr = 1.f / (1.f + expf(-(ir + hr)));
          float zz = 1.f / (1.f + expf(-(iz + hz)));
          float nn = tanhf(in + rr * hn);
          res[e] = (1.f - zz) * nn + zz * ho;
        }
        if (i == 47) {
          out[b*512 + d0]     = res[0];
          out[b*512 + d0 + 1] = res[1];
        } else {
          unsigned long long pk = (unsigned long long)__builtin_bit_cast(unsigned, res[0])
                                | ((unsigned long long)__builtin_bit_cast(unsigned, res[1]) << 32);
          st_a64(h + b*512 + d0, pk);
          st_a32(hbf + b*512 + d0, pack_bf2(res[0], res[1]));
        }
      }
    }
    gbar(bar, ++phase * 32);
  }
}

// ---------------------------------------------------------------------------
extern "C" void kernel_launch(void* const* d_in, const int* in_sizes, int n_in,
                              void* d_out, int out_size, void* d_ws, size_t ws_size,
                              hipStream_t stream) {
  const int*   cpt   = (const int*)d_in[0];
  const float* table = (const float*)d_in[2];
  const float* Weh   = (const float*)d_in[3];
  const float* beh   = (const float*)d_in[4];
  const float* h0    = (const float*)d_in[5];
  const float* Win   = (const float*)d_in[6];
  const float* Wout  = (const float*)d_in[7];
  const float* Wih   = (const float*)d_in[8];
  const float* Whh   = (const float*)d_in[9];
  const float* bih   = (const float*)d_in[10];
  const float* bhh   = (const float*)d_in[11];

  if (ws_size < WS_NEED) return;  // cannot run without workspace

  char* ws = (char*)d_ws;
  bf16_t* mem   = (bf16_t*)(ws);
  bf16_t* WA    = (bf16_t*)(ws + OFF_WA);
  bf16_t* WoutB = (bf16_t*)(ws + OFF_WOUT);
  bf16_t* WihB  = (bf16_t*)(ws + OFF_WIH);
  int*    len   = (int*)(ws + OFF_LEN);
  float*  h     = (float*)(ws + OFF_H);
  bf16_t* hbf   = (bf16_t*)(ws + OFF_HBF);
  float*  q     = (float*)(ws + OFF_Q);
  float*  gh    = (float*)(ws + OFF_GH);
  bf16_t* cbf   = (bf16_t*)(ws + OFF_CBF);
  bf16_t* xbf   = (bf16_t*)(ws + OFF_XBF);
  unsigned* bar = (unsigned*)(ws + OFF_BAR);

  hipMemsetAsync(bar, 0, 256, stream);
  prep_weights<<<9216, 256, 0, stream>>>(Win, Whh, Wout, Wih, WA, WoutB, WihB);
  h_init<<<64, 256, 0, stream>>>(h0, h, hbf);
  lengths_kernel<<<6, 256, 0, stream>>>(cpt, len);
  embed_gemm<<<12288, 256, 0, stream>>>(cpt, table, Weh, beh, mem);
  scan_kernel<<<32, 256, 0, stream>>>(mem, len, WA, WoutB, WihB, bih, bhh,
                                      q, gh, h, hbf, cbf, xbf, bar, (float*)d_out);
}

// Round 3
// 2001.145 us; speedup vs baseline: 1.0723x; 1.0151x over previous
//
#include <hip/hip_runtime.h>
#include <hip/hip_bf16.h>
#include <stdint.h>

// ---------------------------------------------------------------------------
// GraphEncoder. Round 3: precompute P = mem@W_in, Q = mem@Wc^T (removes the
// q-GEMM and c-GEMM from the sequential scan) -> 2 barrier phases per step
// instead of 4. Legacy 4-phase path kept as fallback for small ws_size.
// ---------------------------------------------------------------------------

typedef __bf16 bf16_t;
typedef __bf16 bf16x8 __attribute__((ext_vector_type(8)));
typedef float  f32x4  __attribute__((ext_vector_type(4)));

#define MFMA16(a,b,c) __builtin_amdgcn_mfma_f32_16x16x32_bf16((a),(b),(c),0,0,0)

// ======================= new-path workspace layout ==========================
static constexpr size_t N_MEM   = 0;                        // bf16 [98304][512]
static constexpr size_t N_PQ    = 100663296;                // bf16 [98304][1024] (P|Q)
static constexpr size_t N_WH    = N_PQ + 201326592;         // bf16 [2048][512]  (W_hh ; Wh2)
static constexpr size_t N_W2    = N_WH + 2097152;           // bf16 [1024][512]  (W_in^T ; Wc)
static constexpr size_t N_WI    = N_W2 + 1048576;           // bf16 [1536][512]
static constexpr size_t N_LEN   = N_WI + 1572864;           // int [1536]
static constexpr size_t N_H     = N_LEN + 8192;             // f32 [32][512]
static constexpr size_t N_HBF   = N_H + 65536;              // bf16 [32][512]
static constexpr size_t N_GH    = N_HBF + 32768;            // f32 [32][1536]
static constexpr size_t N_HW2   = N_GH + 196608;            // f32 [32][512]
static constexpr size_t N_XC    = N_HW2 + 65536;            // f32 [32][512]
static constexpr size_t N_BAR   = N_XC + 65536;
static constexpr size_t WS_NEW  = N_BAR + 256;

// ======================= legacy workspace layout ============================
static constexpr size_t L_MEM   = 0;
static constexpr size_t L_WA    = 100663296;
static constexpr size_t L_WOUT  = L_WA + 2097152;
static constexpr size_t L_WIH   = L_WOUT + 1048576;
static constexpr size_t L_LEN   = L_WIH + 1572864;
static constexpr size_t L_H     = L_LEN + 8192;
static constexpr size_t L_HBF   = L_H + 65536;
static constexpr size_t L_Q     = L_HBF + 32768;
static constexpr size_t L_GH    = L_Q + 65536;
static constexpr size_t L_CBF   = L_GH + 196608;
static constexpr size_t L_XBF   = L_CBF + 32768;
static constexpr size_t L_BAR   = L_XBF + 32768;
static constexpr size_t WS_LEG  = L_BAR + 256;

// ---- helpers ----
__device__ __forceinline__ unsigned ld_a32(const void* p) {
  return __hip_atomic_load((const unsigned*)p, __ATOMIC_RELAXED, __HIP_MEMORY_SCOPE_AGENT);
}
__device__ __forceinline__ unsigned long long ld_a64(const void* p) {
  return __hip_atomic_load((const unsigned long long*)p, __ATOMIC_RELAXED, __HIP_MEMORY_SCOPE_AGENT);
}
__device__ __forceinline__ void st_a32(void* p, unsigned v) {
  __hip_atomic_store((unsigned*)p, v, __ATOMIC_RELAXED, __HIP_MEMORY_SCOPE_AGENT);
}
__device__ __forceinline__ void st_a64(void* p, unsigned long long v) {
  __hip_atomic_store((unsigned long long*)p, v, __ATOMIC_RELAXED, __HIP_MEMORY_SCOPE_AGENT);
}
__device__ __forceinline__ float lo_f(unsigned long long u) {
  return __builtin_bit_cast(float, (unsigned)(u & 0xffffffffu));
}
__device__ __forceinline__ float hi_f(unsigned long long u) {
  return __builtin_bit_cast(float, (unsigned)(u >> 32));
}
__device__ __forceinline__ unsigned long long pack_f2(float a, float b) {
  return (unsigned long long)__builtin_bit_cast(unsigned, a)
       | ((unsigned long long)__builtin_bit_cast(unsigned, b) << 32);
}
__device__ __forceinline__ float2 bf2f(unsigned u) {
  float2 r;
  unsigned lo = u << 16, hi = u & 0xffff0000u;
  r.x = __builtin_bit_cast(float, lo);
  r.y = __builtin_bit_cast(float, hi);
  return r;
}
__device__ __forceinline__ unsigned pack_bf2(float a, float b) {
  __bf16 ba = (__bf16)a, bb = (__bf16)b;
  unsigned short ua = __builtin_bit_cast(unsigned short, ba);
  unsigned short ub = __builtin_bit_cast(unsigned short, bb);
  return (unsigned)ua | ((unsigned)ub << 16);
}
__device__ __forceinline__ bf16x8 cvt8(float4 lo, float4 hi) {
  bf16x8 v;
  v[0]=(__bf16)lo.x; v[1]=(__bf16)lo.y; v[2]=(__bf16)lo.z; v[3]=(__bf16)lo.w;
  v[4]=(__bf16)hi.x; v[5]=(__bf16)hi.y; v[6]=(__bf16)hi.z; v[7]=(__bf16)hi.w;
  return v;
}
__device__ __forceinline__ float fsig(float x) {
  return __builtin_amdgcn_rcpf(1.f + __expf(-x));
}
__device__ __forceinline__ float ftanh(float x) {
  float e = __expf(-2.f * fabsf(x));
  float t = (1.f - e) * __builtin_amdgcn_rcpf(1.f + e);
  return __builtin_copysignf(t, x);
}
// monotonic-counter grid barrier, all-relaxed.
__device__ __forceinline__ void gbar(unsigned* cnt, int target) {
  __syncthreads();
  if (threadIdx.x == 0) {
    __hip_atomic_fetch_add(cnt, 1u, __ATOMIC_RELAXED, __HIP_MEMORY_SCOPE_AGENT);
    while ((int)__hip_atomic_load(cnt, __ATOMIC_RELAXED, __HIP_MEMORY_SCOPE_AGENT) < target) {
      __builtin_amdgcn_s_sleep(1);
    }
  }
  __syncthreads();
}

// ======================= shared prep kernels ================================
__global__ __launch_bounds__(256) void h_init(
    const float* __restrict__ h0, float* __restrict__ h, bf16_t* __restrict__ hbf)
{
  int idx = blockIdx.x * 256 + threadIdx.x;   // 16384
  float v = h0[idx & 511];
  h[idx] = v;
  hbf[idx] = (__bf16)v;
}

__global__ __launch_bounds__(256) void lengths_kernel(
    const int* __restrict__ cpt, int* __restrict__ len)
{
  int r = blockIdx.x * 256 + threadIdx.x;
  if (r < 1536) {
    int c = 0;
    for (int s = 0; s < 64; ++s) c += (cpt[r*64 + s] != 0);
    len[r] = c > 1 ? c : 1;
  }
}

// ---- embed GEMM: mem = bf16(elu(emb_table[cpt] @ W_eh^T + b_eh)) ----
__global__ __launch_bounds__(256) void embed_gemm(
    const int* __restrict__ cpt, const float* __restrict__ table,
    const float* __restrict__ Weh, const float* __restrict__ beh,
    bf16_t* __restrict__ mem)
{
  __shared__ unsigned short A_lds[64][40];
  __shared__ unsigned short B_lds[64][40];
  const int bid = blockIdx.x;
  const int M0 = (bid >> 3) * 64;
  const int N0 = (bid & 7) * 64;
  const int tid = threadIdx.x, lane = tid & 63, w = tid >> 6;
  const int l15 = lane & 15, quad = lane >> 4;
  const int srow = tid >> 2;
  const int koff = (tid & 3) * 8;
  const int tok = cpt[M0 + srow];
  const float* arow = table + (size_t)tok * 512;
  const float* brow = Weh + (size_t)(N0 + srow) * 512;

  f32x4 acc0 = {0,0,0,0}, acc1 = {0,0,0,0}, acc2 = {0,0,0,0}, acc3 = {0,0,0,0};
  for (int kt = 0; kt < 16; ++kt) {
    const int k0 = kt * 32;
    float4 alo = *(const float4*)(arow + k0 + koff);
    float4 ahi = *(const float4*)(arow + k0 + koff + 4);
    float4 blo = *(const float4*)(brow + k0 + koff);
    float4 bhi = *(const float4*)(brow + k0 + koff + 4);
    __syncthreads();
    *(bf16x8*)(&A_lds[srow][koff]) = cvt8(alo, ahi);
    *(bf16x8*)(&B_lds[srow][koff]) = cvt8(blo, bhi);
    __syncthreads();
    const int kq = quad * 8;
    bf16x8 bfr = *(const bf16x8*)(&B_lds[16*w + l15][kq]);
    bf16x8 a0 = *(const bf16x8*)(&A_lds[l15][kq]);
    bf16x8 a1 = *(const bf16x8*)(&A_lds[16 + l15][kq]);
    bf16x8 a2 = *(const bf16x8*)(&A_lds[32 + l15][kq]);
    bf16x8 a3 = *(const bf16x8*)(&A_lds[48 + l15][kq]);
    acc0 = MFMA16(a0, bfr, acc0);
    acc1 = MFMA16(a1, bfr, acc1);
    acc2 = MFMA16(a2, bfr, acc2);
    acc3 = MFMA16(a3, bfr, acc3);
  }
  const int n = N0 + 16*w + l15;
  const float bias = beh[n];
  f32x4 accs[4] = {acc0, acc1, acc2, acc3};
  #pragma unroll
  for (int mt = 0; mt < 4; ++mt) {
    #pragma unroll
    for (int r = 0; r < 4; ++r) {
      int m = M0 + mt*16 + quad*4 + r;
      float v = accs[mt][r] + bias;
      v = v > 0.f ? v : expm1f(v);
      int s = m & 63, nrow = m >> 6;
      int sent = nrow % 48, b = nrow / 48;
      mem[(((size_t)(sent*32 + b))*64 + s)*512 + n] = (__bf16)v;
    }
  }
}

// ======================= NEW PATH ==========================================
// prep: WH = [W_hh ; Wh2], W2 = [W_in^T ; Wc], WI = W_ih (all bf16)
__global__ __launch_bounds__(256) void prep_new(
    const float* __restrict__ Win, const float* __restrict__ Whh,
    const float* __restrict__ Wout, const float* __restrict__ Wih,
    bf16_t* __restrict__ WH, bf16_t* __restrict__ W2, bf16_t* __restrict__ WI)
{
  int idx = blockIdx.x * 256 + threadIdx.x;   // 2359296 total
  if (idx < 1048576) {
    int row = idx >> 9, d = idx & 511;
    float v = (row < 1536) ? Whh[row*512 + d] : Wout[(size_t)(row-1536)*1024 + 512 + d];
    WH[idx] = (__bf16)v;
  } else if (idx < 1572864) {
    int t = idx - 1048576;
    int r = t >> 9, d = t & 511;
    float v = (r < 512) ? Win[(size_t)d*512 + r] : Wout[(size_t)(r-512)*1024 + d];
    W2[t] = (__bf16)v;
  } else {
    int t = idx - 1572864;
    WI[t] = (__bf16)Wih[t];
  }
}

// PQ GEMM: PQ[n][0:512]=P=mem@W_in, [512:1024]=Q=mem@Wc^T.
// 128x64 tile, BK=32, grid (98304/128)*(1024/64)=12288 blocks.
__global__ __launch_bounds__(256) void pq_gemm(
    const bf16_t* __restrict__ mem, const bf16_t* __restrict__ W2,
    bf16_t* __restrict__ PQ)
{
  __shared__ unsigned short A_lds[128][40];
  __shared__ unsigned short B_lds[64][40];
  const int bid = blockIdx.x;
  const int M0 = (bid >> 4) * 128;
  const int N0 = (bid & 15) * 64;
  const int tid = threadIdx.x, lane = tid & 63, w = tid >> 6;
  const int l15 = lane & 15, quad = lane >> 4;
  const int arow = tid >> 1, akoff = (tid & 1) * 16;
  const int brow = tid >> 2, bkoff = (tid & 3) * 8;
  const bf16_t* ap = mem + (size_t)(M0 + arow) * 512 + akoff;
  const bf16_t* bp = W2 + (size_t)(N0 + brow) * 512 + bkoff;

  f32x4 acc[2][4];
  #pragma unroll
  for (int mt = 0; mt < 2; ++mt)
    #pragma unroll
    for (int nt = 0; nt < 4; ++nt) acc[mt][nt] = (f32x4){0,0,0,0};

  for (int kt = 0; kt < 16; ++kt) {
    const int k0 = kt * 32;
    bf16x8 a0 = *(const bf16x8*)(ap + k0);
    bf16x8 a1 = *(const bf16x8*)(ap + k0 + 8);
    bf16x8 b0 = *(const bf16x8*)(bp + k0);
    __syncthreads();
    *(bf16x8*)(&A_lds[arow][akoff])     = a0;
    *(bf16x8*)(&A_lds[arow][akoff + 8]) = a1;
    *(bf16x8*)(&B_lds[brow][bkoff])     = b0;
    __syncthreads();
    const int kq = quad * 8;
    bf16x8 af0 = *(const bf16x8*)(&A_lds[32*w + l15][kq]);
    bf16x8 af1 = *(const bf16x8*)(&A_lds[32*w + 16 + l15][kq]);
    #pragma unroll
    for (int nt = 0; nt < 4; ++nt) {
      bf16x8 bf = *(const bf16x8*)(&B_lds[nt*16 + l15][kq]);
      acc[0][nt] = MFMA16(af0, bf, acc[0][nt]);
      acc[1][nt] = MFMA16(af1, bf, acc[1][nt]);
    }
  }
  #pragma unroll
  for (int mt = 0; mt < 2; ++mt) {
    #pragma unroll
    for (int nt = 0; nt < 4; ++nt) {
      #pragma unroll
      for (int r = 0; r < 4; ++r) {
        int m = M0 + 32*w + mt*16 + quad*4 + r;
        int n = N0 + nt*16 + l15;
        PQ[(size_t)m*1024 + n] = (__bf16)acc[mt][nt][r];
      }
    }
  }
}

// ---- 2-phase persistent scan: 64 blocks ----
// P1: blocks 0..31 attention (scores via h.P, softmax, xc = sum align*Q)
//     blocks 32..63 GEMM hW = hbf @ WH^T -> gh (rows<1536), hW2 (rows>=1536)
// P2: all 64 blocks: x = tanh(xc+hW2) (dup), gi slice = x @ WI^T, GRU update
__global__ __launch_bounds__(256) void scan2(
    const bf16_t* __restrict__ PQ, const int* __restrict__ lengths,
    const bf16_t* __restrict__ WH, const bf16_t* __restrict__ WI,
    const float* __restrict__ b_ih, const float* __restrict__ b_hh,
    float* __restrict__ gh, float* __restrict__ hW2, float* __restrict__ xc,
    float* __restrict__ h, bf16_t* __restrict__ hbf,
    unsigned* __restrict__ bar, float* __restrict__ out)
{
  // smem: [0,33280) x_lds / hbf_lds: 32 rows * 1040B
  //       [33280] hsm f32[512]; [35328] sc f32[64]; [35584] al f32[64];
  //       [35840] gi f32[32][33] = 4224 -> end 40064
  __shared__ __align__(16) unsigned char smem[40192];
  unsigned short* x_lds = (unsigned short*)smem;
  float* hsm = (float*)(smem + 33280);
  float* sc_lds = (float*)(smem + 35328);
  float* al_lds = (float*)(smem + 35584);
  float* gi_lds = (float*)(smem + 35840);

  const int g = blockIdx.x, tid = threadIdx.x, lane = tid & 63, w = tid >> 6;
  const int quad = lane >> 4, l15 = lane & 15;
  int phase = 0;

  for (int i = 0; i < 48; ++i) {
    // =========================== phase 1 ===================================
    if (g < 32) {
      // ---- attention for batch g ----
      { int t2 = tid * 2;
        unsigned long long v = ld_a64(h + g*512 + t2);
        hsm[t2] = lo_f(v); hsm[t2+1] = hi_f(v); }
      __syncthreads();
      {
        const int s = tid >> 2, p = tid & 3;
        const bf16_t* prow = PQ + ((size_t)((i*32+g)*64 + s))*1024 + p*128;
        const float* qp = hsm + p*128;
        float sum = 0.f;
        #pragma unroll
        for (int it = 0; it < 16; ++it) {
          uint4 u = ((const uint4*)prow)[it];
          float2 f0 = bf2f(u.x), f1 = bf2f(u.y), f2 = bf2f(u.z), f3 = bf2f(u.w);
          const float* qq = qp + it*8;
          sum += f0.x*qq[0] + f0.y*qq[1] + f1.x*qq[2] + f1.y*qq[3]
               + f2.x*qq[4] + f2.y*qq[5] + f3.x*qq[6] + f3.y*qq[7];
        }
        sum += __shfl_xor(sum, 1);
        sum += __shfl_xor(sum, 2);
        if (p == 0) {
          int len = lengths[g*48 + i];
          sc_lds[s] = (s < len) ? sum : -1e30f;
        }
      }
      __syncthreads();
      if (tid < 64) {
        float v = sc_lds[tid];
        float mx = v;
        #pragma unroll
        for (int o = 32; o; o >>= 1) mx = fmaxf(mx, __shfl_xor(mx, o));
        float e = __expf(v - mx);
        float sm = e;
        #pragma unroll
        for (int o = 32; o; o >>= 1) sm += __shfl_xor(sm, o);
        al_lds[tid] = e * __builtin_amdgcn_rcpf(sm);
      }
      __syncthreads();
      {
        const int d0 = tid * 2;
        const bf16_t* qbase = PQ + ((size_t)((i*32+g)*64))*1024 + 512 + d0;
        float c0 = 0.f, c1 = 0.f;
        for (int s2 = 0; s2 < 64; ++s2) {
          unsigned u = *(const unsigned*)(qbase + (size_t)s2*1024);
          float2 f = bf2f(u);
          float a = al_lds[s2];
          c0 += a * f.x; c1 += a * f.y;
        }
        st_a64(xc + g*512 + d0, pack_f2(c0, c1));
      }
    } else {
      // ---- hW GEMM: rows R0..R0+63 of WH ----
      const int R0 = 64 * (g - 32);
      for (int it = 0; it < 16; ++it) {
        int c = tid + 256*it;
        int row = c >> 7, cc = c & 127;
        unsigned long long v = ld_a64(hbf + row*512 + cc*4);
        *(unsigned long long*)((char*)x_lds + row*1040 + cc*8) = v;
      }
      __syncthreads();
      f32x4 acc[8];
      #pragma unroll
      for (int t = 0; t < 8; ++t) acc[t] = (f32x4){0,0,0,0};
      #pragma unroll
      for (int kt = 0; kt < 16; ++kt) {
        const int k = kt*32 + quad*8;
        bf16x8 a0 = *(const bf16x8*)((char*)x_lds + l15*1040 + k*2);
        bf16x8 a1 = *(const bf16x8*)((char*)x_lds + (16 + l15)*1040 + k*2);
        #pragma unroll
        for (int nt = 0; nt < 4; ++nt) {
          bf16x8 bfr = *(const bf16x8*)(WH + (size_t)(R0 + nt*16 + l15)*512 + k);
          acc[nt]   = MFMA16(a0, bfr, acc[nt]);
          acc[4+nt] = MFMA16(a1, bfr, acc[4+nt]);
        }
      }
      #pragma unroll
      for (int nt = 0; nt < 4; ++nt) {
        const int R = R0 + nt*16 + l15;
        const float bias = (R < 1536) ? b_hh[R] : 0.f;
        #pragma unroll
        for (int mt = 0; mt < 2; ++mt) {
          #pragma unroll
          for (int r = 0; r < 4; ++r) {
            int b = 16*mt + quad*4 + r;
            float v = acc[mt*4 + nt][r] + bias;
            if (R < 1536) st_a32(gh + b*1536 + R, __builtin_bit_cast(unsigned, v));
            else          st_a32(hW2 + b*512 + (R - 1536), __builtin_bit_cast(unsigned, v));
          }
        }
      }
    }
    gbar(bar, ++phase * 64);

    // =========================== phase 2 ===================================
    // x = tanh(xc + hW2) -> x_lds (bf16, padded rows); duplicated per block.
    for (int it = 0; it < 32; ++it) {
      int c2 = tid + 256*it;            // 8192 pairs
      int b = c2 >> 8, dp = c2 & 255, d0 = dp*2;
      unsigned long long xv = ld_a64(xc + b*512 + d0);
      unsigned long long hv = ld_a64(hW2 + b*512 + d0);
      float t0 = ftanh(lo_f(xv) + lo_f(hv));
      float t1 = ftanh(hi_f(xv) + hi_f(hv));
      *(unsigned*)((char*)x_lds + b*1040 + d0*2) = pack_bf2(t0, t1);
    }
    __syncthreads();
    {
      // gi slice: local rows 0..23 = W_ih rows {d, 512+d, 1024+d : d in 8g..8g+7}
      f32x4 ga[4];
      #pragma unroll
      for (int t = 0; t < 4; ++t) ga[t] = (f32x4){0,0,0,0};
      const int lr0 = l15, lr1c = (16 + l15 < 24) ? (16 + l15) : 23;
      const bf16_t* w0 = WI + ((size_t)((lr0 >> 3)*512 + 8*g + (lr0 & 7)))*512;
      const bf16_t* w1 = WI + ((size_t)((lr1c >> 3)*512 + 8*g + (lr1c & 7)))*512;
      #pragma unroll
      for (int kt = 0; kt < 16; ++kt) {
        const int k = kt*32 + quad*8;
        bf16x8 a0 = *(const bf16x8*)((char*)x_lds + l15*1040 + k*2);
        bf16x8 a1 = *(const bf16x8*)((char*)x_lds + (16 + l15)*1040 + k*2);
        bf16x8 b0 = *(const bf16x8*)(w0 + k);
        bf16x8 b1 = *(const bf16x8*)(w1 + k);
        ga[0] = MFMA16(a0, b0, ga[0]);
        ga[1] = MFMA16(a0, b1, ga[1]);
        ga[2] = MFMA16(a1, b0, ga[2]);
        ga[3] = MFMA16(a1, b1, ga[3]);
      }
      #pragma unroll
      for (int nt = 0; nt < 2; ++nt) {
        int lr = nt*16 + l15;
        if (lr < 24) {
          #pragma unroll
          for (int mt = 0; mt < 2; ++mt) {
            #pragma unroll
            for (int r = 0; r < 4; ++r) {
              int b = 16*mt + quad*4 + r;
              gi_lds[lr*33 + b] = ga[mt*2 + nt][r];
            }
          }
        }
      }
    }
    __syncthreads();
    {
      const int b = tid >> 3, dl = tid & 7;
      const int D = 8*g + dl;
      float ir = gi_lds[dl*33 + b]        + b_ih[D];
      float iz = gi_lds[(8+dl)*33 + b]    + b_ih[512 + D];
      float in = gi_lds[(16+dl)*33 + b]   + b_ih[1024 + D];
      float hr = __builtin_bit_cast(float, ld_a32(gh + b*1536 + D));
      float hz = __builtin_bit_cast(float, ld_a32(gh + b*1536 + 512 + D));
      float hn = __builtin_bit_cast(float, ld_a32(gh + b*1536 + 1024 + D));
      float ho = __builtin_bit_cast(float, ld_a32(h + b*512 + D));
      float rr = fsig(ir + hr);
      float zz = fsig(iz + hz);
      float nn = ftanh(in + rr * hn);
      float res = (1.f - zz) * nn + zz * ho;
      if (i == 47) {
        out[b*512 + D] = res;
      } else {
        st_a32(h + b*512 + D, __builtin_bit_cast(unsigned, res));
        float o2 = __shfl_xor(res, 1);
        if ((dl & 1) == 0) st_a32(hbf + b*512 + D, pack_bf2(res, o2));
      }
    }
    gbar(bar, ++phase * 64);
  }
}

// ======================= LEGACY PATH (fallback) =============================
__global__ __launch_bounds__(256) void prep_legacy(
    const float* __restrict__ Win, const float* __restrict__ Whh,
    const float* __restrict__ Wout, const float* __restrict__ Wih,
    bf16_t* __restrict__ WA, bf16_t* __restrict__ WoutB, bf16_t* __restrict__ WihB)
{
  int idx = blockIdx.x * 256 + threadIdx.x;
  if (idx < 262144)        WA[idx]            = (__bf16)Win[idx];
  else if (idx < 1048576)  WA[idx]            = (__bf16)Whh[idx - 262144];
  else if (idx < 1572864)  WoutB[idx-1048576] = (__bf16)Wout[idx - 1048576];
  else if (idx < 2359296)  WihB[idx-1572864]  = (__bf16)Wih[idx - 1572864];
}

__global__ __launch_bounds__(256) void scan_legacy(
    const bf16_t* __restrict__ mem, const int* __restrict__ lengths,
    const bf16_t* __restrict__ WA, const bf16_t* __restrict__ Wout, const bf16_t* __restrict__ Wih,
    const float* __restrict__ b_ih, const float* __restrict__ b_hh,
    float* __restrict__ q, float* __restrict__ gh,
    float* __restrict__ h, bf16_t* __restrict__ hbf,
    bf16_t* __restrict__ cbf, bf16_t* __restrict__ xbf,
    unsigned* __restrict__ bar, float* __restrict__ out)
{
  __shared__ __align__(16) unsigned char smem[52352];
  unsigned short* h_lds = (unsigned short*)smem;
  unsigned short* x_lds = (unsigned short*)smem;
  float* q_lds  = (float*)(smem + 33280);
  float* sc_lds = (float*)(smem + 35328);
  float* al_lds = (float*)(smem + 35584);
  unsigned short* c_lds = (unsigned short*)(smem + 33280);
  float* xb_lds = (float*)(smem + 50176);
  float* gi_lds = (float*)(smem + 33280);

  const int g = blockIdx.x, tid = threadIdx.x, lane = tid & 63, w = tid >> 6;
  const int quad = lane >> 4, l15 = lane & 15;
  int phase = 0;

  for (int i = 0; i < 48; ++i) {
    for (int it = 0; it < 16; ++it) {
      int chunk = tid + 256*it;
      int row = chunk >> 7, cc = chunk & 127;
      unsigned long long v = ld_a64(hbf + row*512 + cc*4);
      *(unsigned long long*)((char*)h_lds + row*1040 + cc*8) = v;
    }
    __syncthreads();
    {
      f32x4 acc0 = {0,0,0,0}, acc1 = {0,0,0,0};
      const int nrow = 64*g + 16*w + l15;
      const bf16_t* wrow = WA + (size_t)nrow * 512;
      #pragma unroll
      for (int kt = 0; kt < 16; ++kt) {
        const int k = kt*32 + quad*8;
        bf16x8 bfr = *(const bf16x8*)(wrow + k);
        bf16x8 a0 = *(const bf16x8*)((char*)h_lds + l15*1040 + k*2);
        bf16x8 a1 = *(const bf16x8*)((char*)h_lds + (16 + l15)*1040 + k*2);
        acc0 = MFMA16(a0, bfr, acc0);
        acc1 = MFMA16(a1, bfr, acc1);
      }
      const float bias = (nrow >= 512) ? b_hh[nrow - 512] : 0.f;
      #pragma unroll
      for (int r = 0; r < 4; ++r) {
        int b0 = quad*4 + r;
        float v0 = acc0[r] + bias, v1 = acc1[r] + bias;
        if (nrow < 512) {
          st_a32(q + b0*512 + nrow,        __builtin_bit_cast(unsigned, v0));
          st_a32(q + (b0+16)*512 + nrow,   __builtin_bit_cast(unsigned, v1));
        } else {
          st_a32(gh + b0*1536 + nrow-512,      __builtin_bit_cast(unsigned, v0));
          st_a32(gh + (b0+16)*1536 + nrow-512, __builtin_bit_cast(unsigned, v1));
        }
      }
    }
    gbar(bar, ++phase * 32);
    {
      for (int it = 0; it < 2; ++it) {
        int idx = tid + 256*it;
        unsigned v = ld_a32(q + g*512 + idx);
        q_lds[idx] = __builtin_bit_cast(float, v);
      }
      __syncthreads();
      const bf16_t* mrow = mem + ((size_t)(i*32 + g)) * 64 * 512;
      {
        const int s = tid >> 2, p = tid & 3;
        const uint4* mp = (const uint4*)(mrow + s*512 + p*128);
        const float* qp = q_lds + p*128;
        float sum = 0.f;
        #pragma unroll
        for (int it = 0; it < 16; ++it) {
          uint4 u = mp[it];
          float2 f0 = bf2f(u.x), f1 = bf2f(u.y), f2 = bf2f(u.z), f3 = bf2f(u.w);
          const float* qq = qp + it*8;
          sum += f0.x*qq[0] + f0.y*qq[1] + f1.x*qq[2] + f1.y*qq[3]
               + f2.x*qq[4] + f2.y*qq[5] + f3.x*qq[6] + f3.y*qq[7];
        }
        sum += __shfl_xor(sum, 1);
        sum += __shfl_xor(sum, 2);
        if (p == 0) {
          int len = lengths[g*48 + i];
          sc_lds[s] = (s < len) ? sum : -1e30f;
        }
      }
      __syncthreads();
      if (tid < 64) {
        float v = sc_lds[tid];
        float mx = v;
        #pragma unroll
        for (int o = 32; o; o >>= 1) mx = fmaxf(mx, __shfl_xor(mx, o));
        float e = __expf(v - mx);
        float sm = e;
        #pragma unroll
        for (int o = 32; o; o >>= 1) sm += __shfl_xor(sm, o);
        al_lds[tid] = e / sm;
      }
      __syncthreads();
      {
        const int d0 = tid * 2;
        float c0 = 0.f, c1 = 0.f;
        for (int s2 = 0; s2 < 64; ++s2) {
          unsigned u = *(const unsigned*)(mrow + s2*512 + d0);
          float2 f = bf2f(u);
          float a = al_lds[s2];
          c0 += a * f.x; c1 += a * f.y;
        }
        st_a32(cbf + g*512 + d0, pack_bf2(c0, c1));
      }
    }
    gbar(bar, ++phase * 32);
    {
      f32x4 acc = {0,0,0,0};
      const int nrow = 16*g + l15;
      const bf16_t* wrow = Wout + (size_t)nrow * 1024;
      for (int kh = 0; kh < 2; ++kh) {
        for (int it = 0; it < 8; ++it) {
          int cid = tid + 256*it;
          int row = cid >> 6, cc = cid & 63;
          unsigned long long v = ld_a64(cbf + row*512 + kh*256 + cc*4);
          *(unsigned long long*)((char*)c_lds + row*528 + cc*8) = v;
        }
        __syncthreads();
        if (w < 2) {
          #pragma unroll
          for (int kt = 0; kt < 8; ++kt) {
            const int kl = kt*32 + quad*8;
            bf16x8 bfr = *(const bf16x8*)(wrow + kh*256 + kl);
            bf16x8 af  = *(const bf16x8*)((char*)c_lds + (16*w + l15)*528 + kl*2);
            acc = MFMA16(af, bfr, acc);
          }
        }
        __syncthreads();
      }
      if (w < 2) {
        #pragma unroll
        for (int kt = 0; kt < 16; ++kt) {
          const int k = kt*32 + quad*8;
          bf16x8 bfr = *(const bf16x8*)(wrow + 512 + k);
          bf16x8 af  = *(const bf16x8*)((char*)h_lds + (16*w + l15)*1040 + k*2);
          acc = MFMA16(af, bfr, acc);
        }
        #pragma unroll
        for (int r = 0; r < 4; ++r)
          xb_lds[w*272 + l15*17 + quad*4 + r] = acc[r];
      }
      __syncthreads();
      {
        const int b = tid >> 3, np = tid & 7;
        const int mt = b >> 4, ml = b & 15;
        float v0 = ftanh(xb_lds[mt*272 + (2*np)*17 + ml]);
        float v1 = ftanh(xb_lds[mt*272 + (2*np+1)*17 + ml]);
        st_a32(xbf + b*512 + 16*g + 2*np, pack_bf2(v0, v1));
      }
    }
    gbar(bar, ++phase * 32);
    {
      for (int it = 0; it < 16; ++it) {
        int chunk = tid + 256*it;
        int row = chunk >> 7, cc = chunk & 127;
        unsigned long long v = ld_a64(xbf + row*512 + cc*4);
        *(unsigned long long*)((char*)x_lds + row*1040 + cc*8) = v;
      }
      __syncthreads();
      #pragma unroll
      for (int tt = 0; tt < 2; ++tt) {
        const int t = w + 4*tt;
        if (t < 6) {
          const int nt = t % 3, mt = t / 3;
          f32x4 acc = {0,0,0,0};
          const int nrow = nt*512 + 16*g + l15;
          const bf16_t* wrow = Wih + (size_t)nrow * 512;
          #pragma unroll
          for (int kt = 0; kt < 16; ++kt) {
            const int k = kt*32 + quad*8;
            bf16x8 bfr = *(const bf16x8*)(wrow + k);
            bf16x8 af  = *(const bf16x8*)((char*)x_lds + (16*mt + l15)*1040 + k*2);
            acc = MFMA16(af, bfr, acc);
          }
          #pragma unroll
          for (int r = 0; r < 4; ++r)
            gi_lds[t*272 + l15*17 + quad*4 + r] = acc[r];
        }
      }
      __syncthreads();
      {
        const int b = tid >> 3, dlp = tid & 7;
        const int mt = b >> 4, ml = b & 15;
        const int d0 = 16*g + 2*dlp;
        unsigned long long ur = ld_a64(gh + b*1536 + d0);
        unsigned long long uz = ld_a64(gh + b*1536 + 512 + d0);
        unsigned long long un = ld_a64(gh + b*1536 + 1024 + d0);
        unsigned long long uh = ld_a64(h + b*512 + d0);
        float res[2];
        #pragma unroll
        for (int e = 0; e < 2; ++e) {
          int dl = 2*dlp + e;
          float ir = gi_lds[(mt*3+0)*272 + dl*17 + ml] + b_ih[16*g + dl];
          float iz = gi_lds[(mt*3+1)*272 + dl*17 + ml] + b_ih[512 + 16*g + dl];
          float in = gi_lds[(mt*3+2)*272 + dl*17 + ml] + b_ih[1024 + 16*g + dl];
          float hr = e ? hi_f(ur) : lo_f(ur);
          float hz = e ? hi_f(uz) : lo_f(uz);
          float hn = e ? hi_f(un) : lo_f(un);
          float ho = e ? hi_f(uh) : lo_f(uh);
          float rr = fsig(ir + hr);
          float zz = fsig(iz + hz);
          float nn = ftanh(in + rr * hn);
          res[e] = (1.f - zz) * nn + zz * ho;
        }
        if (i == 47) {
          out[b*512 + d0]     = res[0];
          out[b*512 + d0 + 1] = res[1];
        } else {
          st_a64(h + b*512 + d0, pack_f2(res[0], res[1]));
          st_a32(hbf + b*512 + d0, pack_bf2(res[0], res[1]));
        }
      }
    }
    gbar(bar, ++phase * 32);
  }
}

// ---------------------------------------------------------------------------
extern "C" void kernel_launch(void* const* d_in, const int* in_sizes, int n_in,
                              void* d_out, int out_size, void* d_ws, size_t ws_size,
                              hipStream_t stream) {
  const int*   cpt   = (const int*)d_in[0];
  const float* table = (const float*)d_in[2];
  const float* Weh   = (const float*)d_in[3];
  const float* beh   = (const float*)d_in[4];
  const float* h0    = (const float*)d_in[5];
  const float* Win   = (const float*)d_in[6];
  const float* Wout  = (const float*)d_in[7];
  const float* Wih   = (const float*)d_in[8];
  const float* Whh   = (const float*)d_in[9];
  const float* bih   = (const float*)d_in[10];
  const float* bhh   = (const float*)d_in[11];
  char* ws = (char*)d_ws;

  if (ws_size >= WS_NEW) {
    bf16_t* mem = (bf16_t*)(ws + N_MEM);
    bf16_t* PQ  = (bf16_t*)(ws + N_PQ);
    bf16_t* WH  = (bf16_t*)(ws + N_WH);
    bf16_t* W2  = (bf16_t*)(ws + N_W2);
    bf16_t* WI  = (bf16_t*)(ws + N_WI);
    int*    len = (int*)(ws + N_LEN);
    float*  h   = (float*)(ws + N_H);
    bf16_t* hbf = (bf16_t*)(ws + N_HBF);
    float*  gh  = (float*)(ws + N_GH);
    float*  hW2 = (float*)(ws + N_HW2);
    float*  xc  = (float*)(ws + N_XC);
    unsigned* bar = (unsigned*)(ws + N_BAR);

    hipMemsetAsync(bar, 0, 256, stream);
    prep_new<<<9216, 256, 0, stream>>>(Win, Whh, Wout, Wih, WH, W2, WI);
    h_init<<<64, 256, 0, stream>>>(h0, h, hbf);
    lengths_kernel<<<6, 256, 0, stream>>>(cpt, len);
    embed_gemm<<<12288, 256, 0, stream>>>(cpt, table, Weh, beh, mem);
    pq_gemm<<<12288, 256, 0, stream>>>(mem, W2, PQ);
    scan2<<<64, 256, 0, stream>>>(PQ, len, WH, WI, bih, bhh,
                                  gh, hW2, xc, h, hbf, bar, (float*)d_out);
  } else if (ws_size >= WS_LEG) {
    bf16_t* mem   = (bf16_t*)(ws + L_MEM);
    bf16_t* WA    = (bf16_t*)(ws + L_WA);
    bf16_t* WoutB = (bf16_t*)(ws + L_WOUT);
    bf16_t* WihB  = (bf16_t*)(ws + L_WIH);
    int*    len   = (int*)(ws + L_LEN);
    float*  h     = (float*)(ws + L_H);
    bf16_t* hbf   = (bf16_t*)(ws + L_HBF);
    float*  q     = (float*)(ws + L_Q);
    float*  gh    = (float*)(ws + L_GH);
    bf16_t* cbf   = (bf16_t*)(ws + L_CBF);
    bf16_t* xbf   = (bf16_t*)(ws + L_XBF);
    unsigned* bar = (unsigned*)(ws + L_BAR);

    hipMemsetAsync(bar, 0, 256, stream);
    prep_legacy<<<9216, 256, 0, stream>>>(Win, Whh, Wout, Wih, WA, WoutB, WihB);
    h_init<<<64, 256, 0, stream>>>(h0, h, hbf);
    lengths_kernel<<<6, 256, 0, stream>>>(cpt, len);
    embed_gemm<<<12288, 256, 0, stream>>>(cpt, table, Weh, beh, mem);
    scan_legacy<<<32, 256, 0, stream>>>(mem, len, WA, WoutB, WihB, bih, bhh,
                                        q, gh, h, hbf, cbf, xbf, bar, (float*)d_out);
  }
}